// Round 1
// baseline (739.726 us; speedup 1.0000x reference)
//
#include <hip/hip_runtime.h>
#include <cstdint>
#include <cstddef>

#define NEG_INF (-__builtin_inff())
#define IMAX 0x7fffffff

constexpr int Bc = 32, Kc = 5, Tc = 12, Vc = 50257, Hc = 512;
constexpr int FLAT  = Kc * Vc;                    // 251285
constexpr int SPLIT = 16;
constexpr int CHUNK = (FLAT + SPLIT - 1) / SPLIT; // 15706 (< Vc, so <=1 beam boundary per chunk)
constexpr int NROWS = Bc * Kc * (Tc + 1);         // 2080 output rows of V floats
constexpr int STATE_N = 2 * Bc * Kc * Hc;         // 163840
constexpr int SMALL_N = STATE_N + NROWS + Bc * Kc; // 166080

// d_out layout (all float32, outputs concatenated in return order):
constexpr long long OUT0 = 0;                             // beam_seq_new        (2080)
constexpr long long OUT1 = NROWS;                         // beam_seq_logprobs_new (2080*V)
constexpr long long OUT2 = OUT1 + (long long)NROWS * Vc;  // beam_logprobs_sum_new (160)
constexpr long long OUT3 = OUT2 + Bc * Kc;                // state_new           (163840)

// ---------------- Phase A: per-chunk top-5 ----------------
__global__ __launch_bounds__(256) void topk_a(
    const float* __restrict__ logprobs, const float* __restrict__ bls,
    float* __restrict__ cand_val, int* __restrict__ cand_idx) {
  const int blk = blockIdx.x;
  const int b = blk / SPLIT;
  const int chunk = blk % SPLIT;
  const int start = chunk * CHUNK;
  const int end = min(start + CHUNK, FLAT);
  const int tid = threadIdx.x;

  // chunk spans at most beams j0 and j0+1
  const int j0 = start / Vc;
  const int boundary = (j0 + 1) * Vc;
  const float s0 = bls[b * Kc + j0];
  const float s1 = bls[b * Kc + min(j0 + 1, Kc - 1)];

  const float* lp = logprobs + (size_t)b * FLAT; // lp[f] == logprobs[(b*K+j)*V + v]

  float lv0 = NEG_INF, lv1 = NEG_INF, lv2 = NEG_INF, lv3 = NEG_INF, lv4 = NEG_INF;
  int li0 = IMAX, li1 = IMAX, li2 = IMAX, li3 = IMAX, li4 = IMAX;

  for (int f = start + tid; f < end; f += 256) {
    float val = ((f < boundary) ? s0 : s1) + lp[f];
    // within-thread f strictly increases -> strict > keeps lower index first on ties
    if (val > lv4) {
      if (val > lv2) {
        if (val > lv1) {
          if (val > lv0) { lv4=lv3; li4=li3; lv3=lv2; li3=li2; lv2=lv1; li2=li1; lv1=lv0; li1=li0; lv0=val; li0=f; }
          else           { lv4=lv3; li4=li3; lv3=lv2; li3=li2; lv2=lv1; li2=li1; lv1=val; li1=f; }
        } else           { lv4=lv3; li4=li3; lv3=lv2; li3=li2; lv2=val; li2=f; }
      } else {
        if (val > lv3)   { lv4=lv3; li4=li3; lv3=val; li3=f; }
        else             { lv4=val; li4=f; }
      }
    }
  }

  __shared__ float sv[256 * 5];
  __shared__ int   si[256 * 5];
  sv[tid*5+0]=lv0; si[tid*5+0]=li0;
  sv[tid*5+1]=lv1; si[tid*5+1]=li1;
  sv[tid*5+2]=lv2; si[tid*5+2]=li2;
  sv[tid*5+3]=lv3; si[tid*5+3]=li3;
  sv[tid*5+4]=lv4; si[tid*5+4]=li4;
  __syncthreads();

  for (int r = 0; r < 5; r++) {
    if (tid < 64) {
      float bv = NEG_INF; int bi = IMAX; int bs = 0;
      for (int c = tid; c < 1280; c += 64) {
        float cv = sv[c]; int ci = si[c];
        if (cv > bv || (cv == bv && ci < bi)) { bv = cv; bi = ci; bs = c; }
      }
      for (int m = 32; m >= 1; m >>= 1) {
        float ov = __shfl_xor(bv, m, 64);
        int   oi = __shfl_xor(bi, m, 64);
        int   os = __shfl_xor(bs, m, 64);
        if (ov > bv || (ov == bv && oi < bi)) { bv = ov; bi = oi; bs = os; }
      }
      if (tid == 0) {
        cand_val[blk * 5 + r] = bv;
        cand_idx[blk * 5 + r] = bi;
        sv[bs] = NEG_INF; si[bs] = IMAX;
      }
    }
    __syncthreads();
  }
}

// ---------------- Phase B: merge 16*5 candidates per batch ----------------
__global__ __launch_bounds__(64) void topk_b(
    const float* __restrict__ cand_val, const int* __restrict__ cand_idx,
    int* __restrict__ beam_ix, int* __restrict__ sel, float* __restrict__ ys) {
  const int b = blockIdx.x;
  const int lane = threadIdx.x;
  __shared__ float sv[SPLIT * 5];
  __shared__ int   si[SPLIT * 5];
  for (int c = lane; c < SPLIT * 5; c += 64) {
    sv[c] = cand_val[b * SPLIT * 5 + c];
    si[c] = cand_idx[b * SPLIT * 5 + c];
  }
  __syncthreads();
  for (int r = 0; r < 5; r++) {
    float bv = NEG_INF; int bi = IMAX; int bs = 0;
    for (int c = lane; c < SPLIT * 5; c += 64) {
      float cv = sv[c]; int ci = si[c];
      if (cv > bv || (cv == bv && ci < bi)) { bv = cv; bi = ci; bs = c; }
    }
    for (int m = 32; m >= 1; m >>= 1) {
      float ov = __shfl_xor(bv, m, 64);
      int   oi = __shfl_xor(bi, m, 64);
      int   os = __shfl_xor(bs, m, 64);
      if (ov > bv || (ov == bv && oi < bi)) { bv = ov; bi = oi; bs = os; }
    }
    if (lane == 0) {
      int j = bi / Vc;
      beam_ix[b * Kc + r] = j;
      sel[b * Kc + r]     = bi - j * Vc;
      ys[b * Kc + r]      = bv;
      sv[bs] = NEG_INF; si[bs] = IMAX;
    }
    __syncthreads();
  }
}

// ---------------- Small outputs: beam_seq_new, beam_logprobs_sum_new, state_new ----------------
__global__ __launch_bounds__(256) void small_out(
    const int* __restrict__ beam_seq, const float* __restrict__ state,
    const int* __restrict__ beam_ix, const int* __restrict__ sel,
    const float* __restrict__ ys, float* __restrict__ out) {
  int idx = blockIdx.x * 256 + threadIdx.x;
  if (idx < STATE_N) {
    int s   = idx / (Bc * Kc * Hc);
    int rem = idx % (Bc * Kc * Hc);
    int bk  = rem / Hc;
    int h   = rem % Hc;
    int b = bk / Kc, k = bk % Kc;
    int j = beam_ix[b * Kc + k];
    out[OUT3 + idx] = state[(size_t)s * Bc * Kc * Hc + (size_t)(b * Kc + j) * Hc + h];
  } else if (idx < STATE_N + NROWS) {
    int e   = idx - STATE_N;
    int b   = e / (Kc * (Tc + 1));
    int rem = e % (Kc * (Tc + 1));
    int k = rem / (Tc + 1), t = rem % (Tc + 1);
    int bk = b * Kc + k;
    int j = beam_ix[bk];
    float val = (t < Tc) ? (float)beam_seq[(b * Kc + j) * Tc + t] : (float)sel[bk];
    out[OUT0 + e] = val;
  } else if (idx < SMALL_N) {
    int e = idx - (STATE_N + NROWS);
    out[OUT2 + e] = ys[e];
  }
}

// ---------------- Big copy: beam_seq_logprobs_new rows ----------------
__global__ __launch_bounds__(256) void big_copy(
    const float* __restrict__ bslp, const float* __restrict__ unaug,
    const int* __restrict__ beam_ix, float* __restrict__ out) {
  const int r   = blockIdx.x;             // (b,k,t), t in [0,13)
  const int b   = r / (Kc * (Tc + 1));
  const int rem = r % (Kc * (Tc + 1));
  const int k = rem / (Tc + 1), t = rem % (Tc + 1);
  const int j = beam_ix[b * Kc + k];

  const float* src = (t < Tc)
      ? bslp + (size_t)((b * Kc + j) * Tc + t) * Vc
      : unaug + (size_t)(b * Kc + j) * Vc;
  float* dst = out + OUT1 + (size_t)r * Vc;

  const int tid  = threadIdx.x;
  // OUT1 = 2080 (==0 mod 4), Vc == 1 mod 4 -> dest misalignment = r mod 4
  const int head = (4 - (r & 3)) & 3;
  const int n4   = (Vc - head) >> 2;

  const float* s = src + head;
  float*       d = dst + head;            // 16B-aligned
  float4*      d4 = (float4*)d;

  if ((((uintptr_t)s) & 15) == 0) {
    const float4* s4 = (const float4*)s;
    for (int g = tid; g < n4; g += 256) d4[g] = s4[g];
  } else {
    for (int g = tid; g < n4; g += 256) {
      int e = g * 4;
      float4 v; v.x = s[e]; v.y = s[e + 1]; v.z = s[e + 2]; v.w = s[e + 3];
      d4[g] = v;
    }
  }
  if (tid < head) dst[tid] = src[tid];
  const int tb   = head + n4 * 4;
  const int rem2 = Vc - tb;               // 0..3 tail elements
  if (tid >= 64 && tid < 64 + rem2) { int e = tb + (tid - 64); dst[e] = src[e]; }
}

extern "C" void kernel_launch(void* const* d_in, const int* in_sizes, int n_in,
                              void* d_out, int out_size, void* d_ws, size_t ws_size,
                              hipStream_t stream) {
  const float* logprobs = (const float*)d_in[0];   // (B*K, V) f32
  const float* unaug    = (const float*)d_in[1];   // (B*K, V) f32
  const int*   beam_seq = (const int*)d_in[2];     // (B, K, T) int
  const float* bslp     = (const float*)d_in[3];   // (B, K, T, V) f32
  const float* bls      = (const float*)d_in[4];   // (B, K) f32
  const float* state    = (const float*)d_in[5];   // (2, B*K, H) f32
  float* out = (float*)d_out;

  // workspace layout
  float* cand_val = (float*)d_ws;                                    // 2560 f32
  int*   cand_idx = (int*)((char*)d_ws + Bc * SPLIT * 5 * 4);        // 2560 i32
  int*   beam_ix  = (int*)((char*)d_ws + 2 * Bc * SPLIT * 5 * 4);    // 160
  int*   sel      = beam_ix + Bc * Kc;                               // 160
  float* ys       = (float*)(sel + Bc * Kc);                         // 160

  topk_a<<<Bc * SPLIT, 256, 0, stream>>>(logprobs, bls, cand_val, cand_idx);
  topk_b<<<Bc, 64, 0, stream>>>(cand_val, cand_idx, beam_ix, sel, ys);
  small_out<<<(SMALL_N + 255) / 256, 256, 0, stream>>>(beam_seq, state, beam_ix, sel, ys, out);
  big_copy<<<NROWS, 256, 0, stream>>>(bslp, unaug, beam_ix, out);
}